// Round 2
// baseline (112.357 us; speedup 1.0000x reference)
//
#include <hip/hip_runtime.h>
#include <hip/hip_bf16.h>

// Shapes
#define B_SZ   256
#define C_SZ   1024
#define HW     49
#define KDIM   50176        // C*H*W
#define DHID   768
#define NCLS   5

typedef __bf16 bf16x8 __attribute__((ext_vector_type(8)));
typedef __bf16 bf16x4 __attribute__((ext_vector_type(4)));
typedef float  f32x4  __attribute__((ext_vector_type(4)));

#define GLOAD_LDS16(gsrc, ldst) \
  __builtin_amdgcn_global_load_lds((__attribute__((address_space(1))) void*)(gsrc), \
                                   (__attribute__((address_space(3))) void*)(ldst), 16, 0, 0)

// ---------------------------------------------------------------------------
// Kernel A: per-(b,c) spatial max, pcam = feat*max -> bf16 (ws), copy feat -> out
// ---------------------------------------------------------------------------
__global__ __launch_bounds__(256) void pcam_kernel(const float* __restrict__ feat,
                                                   float* __restrict__ feat_out,
                                                   __bf16* __restrict__ pcam) {
  __shared__ float sv[1568];
  __shared__ float smax[32];
  const int tid = threadIdx.x;
  const size_t base = (size_t)blockIdx.x * 1568;

  const float4* src4 = (const float4*)(feat + base);
  float4* dst4 = (float4*)(feat_out + base);
  #pragma unroll
  for (int i = 0; i < 2; ++i) {
    int idx = tid + i * 256;
    if (idx < 392) {
      float4 v = src4[idx];
      dst4[idx] = v;
      ((float4*)sv)[idx] = v;
    }
  }
  __syncthreads();

  {
    const int r = tid >> 3, p = tid & 7;
    float mx = -INFINITY;
    for (int i = p; i < HW; i += 8) mx = fmaxf(mx, sv[r * HW + i]);
    #pragma unroll
    for (int off = 1; off < 8; off <<= 1) mx = fmaxf(mx, __shfl_xor(mx, off));
    if (p == 0) smax[r] = mx;
  }
  __syncthreads();

  for (int i = tid; i < 1568; i += 256) {
    int r = (i * 1338) >> 16;        // i/49 exact for i<1568
    float v = sv[i] * smax[r];
    pcam[base + i] = (__bf16)v;
  }
}

// ---------------------------------------------------------------------------
// Kernel B: split-K bf16 MFMA GEMM, double-buffered LDS, async staging.
// BM=128 BN=128 BK=64, 8 waves (2M x 4N), 2 blocks/CU.
// A: global_load_lds (pre-swizzled global addr -> linear LDS).
// B: T14 split — global->regs issued before compute, cvt+swizzled ds_write after.
// XOR swizzle: 16B-block index ^= (row&7) -> 2-way max on ds_read_b128.
// ---------------------------------------------------------------------------
#define BM 128
#define BN 128
#define BK 64
#define MT 2
#define NT 6
#define KSPLIT 42
#define KSTEPS 784          // KDIM/BK

__global__ __launch_bounds__(512, 4) void gemm1_kernel(const __bf16* __restrict__ pcam,
                                                       const float* __restrict__ W1,
                                                       float* __restrict__ h_acc) {
  __shared__ __bf16 Asm[2][BM * BK];   // 2 x 16KB
  __shared__ __bf16 Bsm[2][BN * BK];   // 2 x 16KB

  const int tid  = threadIdx.x;
  const int lane = tid & 63;
  const int w    = tid >> 6;        // 0..7
  const int wm   = w >> 2;          // 0..1 (64-row slab)
  const int wn   = w & 3;           // 0..3 (32-col slab)
  const int bx   = blockIdx.x;      // 0..11
  const int m0   = (bx & 1) * BM;
  const int n0   = (bx >> 1) * BN;
  const int ks   = blockIdx.y;
  const int s0   = (ks * KSTEPS) / KSPLIT;
  const int s1   = ((ks + 1) * KSTEPS) / KSPLIT;

  const int nb = tid >> 4;          // 0..31: B row within 32-row group
  const int kq = tid & 15;          // float4 index within row
  const int kb = kq >> 1;           // 16B-block within row
  const int sub = (kq & 1) << 3;    // byte offset within 16B block

  f32x4 acc[4][2];
  #pragma unroll
  for (int i = 0; i < 4; ++i)
    #pragma unroll
    for (int j = 0; j < 2; ++j) acc[i][j] = f32x4{0.f, 0.f, 0.f, 0.f};

  float4 br0, br1, br2, br3;

#define LOAD_B(s) do { \
    const size_t koff_ = (size_t)(s) * BK + kq * 4; \
    br0 = *(const float4*)(W1 + (size_t)(n0 + 0  + nb) * KDIM + koff_); \
    br1 = *(const float4*)(W1 + (size_t)(n0 + 32 + nb) * KDIM + koff_); \
    br2 = *(const float4*)(W1 + (size_t)(n0 + 64 + nb) * KDIM + koff_); \
    br3 = *(const float4*)(W1 + (size_t)(n0 + 96 + nb) * KDIM + koff_); \
  } while (0)

#define STAGE_A(bi, s) do { \
    const int k0_ = (s) * BK; \
    _Pragma("unroll") \
    for (int it = 0; it < 2; ++it) { \
      const int q   = it * 512 + tid; \
      const int m   = q >> 3; \
      const int kbl = (q & 7) ^ (m & 7); \
      const __bf16* src = pcam + (size_t)(m0 + m) * KDIM + k0_ + kbl * 8; \
      GLOAD_LDS16(src, &Asm[bi][(size_t)(it * 512 + w * 64) * 8]); \
    } \
  } while (0)

#define WRITE_B(bi) do { \
    _Pragma("unroll") \
    for (int it = 0; it < 4; ++it) { \
      const float4 v = (it == 0) ? br0 : (it == 1) ? br1 : (it == 2) ? br2 : br3; \
      bf16x4 bv; \
      bv[0] = (__bf16)v.x; bv[1] = (__bf16)v.y; bv[2] = (__bf16)v.z; bv[3] = (__bf16)v.w; \
      const int n = it * 32 + nb; \
      const int phys = n * 128 + (((kb ^ (n & 7)) << 4) | sub); \
      *(bf16x4*)((char*)Bsm[bi] + phys) = bv; \
    } \
  } while (0)

#define COMPUTE(bi) do { \
    _Pragma("unroll") \
    for (int ksub = 0; ksub < 2; ++ksub) { \
      bf16x8 af[4], bfr[2]; \
      const int kb2 = ksub * 4 + (lane >> 4); \
      _Pragma("unroll") \
      for (int i = 0; i < 4; ++i) { \
        const int m = wm * 64 + i * 16 + (lane & 15); \
        af[i] = *(const bf16x8*)((const char*)Asm[bi] + m * 128 + ((kb2 ^ (m & 7)) << 4)); \
      } \
      _Pragma("unroll") \
      for (int j = 0; j < 2; ++j) { \
        const int n = wn * 32 + j * 16 + (lane & 15); \
        bfr[j] = *(const bf16x8*)((const char*)Bsm[bi] + n * 128 + ((kb2 ^ (n & 7)) << 4)); \
      } \
      _Pragma("unroll") \
      for (int i = 0; i < 4; ++i) \
        _Pragma("unroll") \
        for (int j = 0; j < 2; ++j) \
          acc[i][j] = __builtin_amdgcn_mfma_f32_16x16x32_bf16(af[i], bfr[j], acc[i][j], 0, 0, 0); \
    } \
  } while (0)

  // prologue
  LOAD_B(s0);
  STAGE_A(0, s0);
  WRITE_B(0);
  __syncthreads();

  int buf = 0;
  for (int s = s0; s < s1; ++s) {
    const int nxt = s + 1;
    if (nxt < s1) {
      LOAD_B(nxt);            // HBM -> regs, consumed after compute
      STAGE_A(buf ^ 1, nxt);  // async DMA into other buffer
    }
    COMPUTE(buf);
    if (nxt < s1) WRITE_B(buf ^ 1);
    __syncthreads();          // drains vmcnt (A DMA) + syncs buffer swap
    buf ^= 1;
  }

  // epilogue: split-K accumulate (C/D layout: col=lane&15, row=(lane>>4)*4+r)
  #pragma unroll
  for (int i = 0; i < 4; ++i) {
    const int mb = m0 + wm * 64 + i * 16 + (lane >> 4) * 4;
    #pragma unroll
    for (int j = 0; j < 2; ++j) {
      const int n = n0 + wn * 32 + j * 16 + (lane & 15);
      #pragma unroll
      for (int r = 0; r < 4; ++r)
        unsafeAtomicAdd(&h_acc[(size_t)(mb + r) * DHID + n], acc[i][j][r]);
    }
  }
#undef LOAD_B
#undef STAGE_A
#undef WRITE_B
#undef COMPUTE
}

// ---------------------------------------------------------------------------
// Kernel C: h = relu(h_acc + b1); logits = h @ W2^T + b2. One wave per batch row.
// ---------------------------------------------------------------------------
__global__ __launch_bounds__(64) void head_kernel(const float* __restrict__ h_acc,
                                                  const float* __restrict__ b1,
                                                  const float* __restrict__ W2,
                                                  const float* __restrict__ b2,
                                                  float* __restrict__ logits) {
  const int m = blockIdx.x;
  const int lane = threadIdx.x;
  float hv[12];
  #pragma unroll
  for (int j = 0; j < 12; ++j) {
    float v = h_acc[(size_t)m * DHID + j * 64 + lane] + b1[j * 64 + lane];
    hv[j] = v > 0.f ? v : 0.f;
  }
  #pragma unroll
  for (int c = 0; c < NCLS; ++c) {
    float s = 0.f;
    #pragma unroll
    for (int j = 0; j < 12; ++j) s += hv[j] * W2[c * DHID + j * 64 + lane];
    #pragma unroll
    for (int off = 32; off > 0; off >>= 1) s += __shfl_xor(s, off);
    if (lane == 0) logits[m * NCLS + c] = s + b2[c];
  }
}

// ---------------------------------------------------------------------------
extern "C" void kernel_launch(void* const* d_in, const int* in_sizes, int n_in,
                              void* d_out, int out_size, void* d_ws, size_t ws_size,
                              hipStream_t stream) {
  const float* feat = (const float*)d_in[0];
  const float* W1   = (const float*)d_in[1];
  const float* b1   = (const float*)d_in[2];
  const float* W2   = (const float*)d_in[3];
  const float* b2   = (const float*)d_in[4];

  float* logits   = (float*)d_out;
  float* feat_out = (float*)d_out + (size_t)B_SZ * NCLS;

  __bf16* pcam  = (__bf16*)d_ws;
  float*  h_acc = (float*)((char*)d_ws + (size_t)B_SZ * KDIM * 2);

  hipMemsetAsync(h_acc, 0, (size_t)B_SZ * DHID * sizeof(float), stream);
  pcam_kernel<<<(B_SZ * C_SZ) / 32, 256, 0, stream>>>(feat, feat_out, pcam);
  gemm1_kernel<<<dim3(MT * NT, KSPLIT), 512, 0, stream>>>(pcam, W1, h_acc);
  head_kernel<<<B_SZ, 64, 0, stream>>>(h_acc, b1, W2, b2, logits);
}

// Round 4
// 107.910 us; speedup vs baseline: 1.0412x; 1.0412x over previous
//
#include <hip/hip_runtime.h>
#include <hip/hip_bf16.h>

// Shapes
#define B_SZ   256
#define C_SZ   1024
#define HW     49
#define KDIM   50176        // C*H*W
#define DHID   768
#define NCLS   5

typedef __bf16 bf16x8 __attribute__((ext_vector_type(8)));
typedef __bf16 bf16x4 __attribute__((ext_vector_type(4)));
typedef float  f32x4  __attribute__((ext_vector_type(4)));

// ---------------------------------------------------------------------------
// Kernel A: per-(b,c) spatial max, pcam = feat*max -> bf16 (ws), copy feat -> out
// ---------------------------------------------------------------------------
__global__ __launch_bounds__(256) void pcam_kernel(const float* __restrict__ feat,
                                                   float* __restrict__ feat_out,
                                                   __bf16* __restrict__ pcam) {
  __shared__ float sv[1568];
  __shared__ float smax[32];
  const int tid = threadIdx.x;
  const size_t base = (size_t)blockIdx.x * 1568;

  const float4* src4 = (const float4*)(feat + base);
  float4* dst4 = (float4*)(feat_out + base);
  #pragma unroll
  for (int i = 0; i < 2; ++i) {
    int idx = tid + i * 256;
    if (idx < 392) {
      float4 v = src4[idx];
      dst4[idx] = v;
      ((float4*)sv)[idx] = v;
    }
  }
  __syncthreads();

  {
    const int r = tid >> 3, p = tid & 7;
    float mx = -INFINITY;
    for (int i = p; i < HW; i += 8) mx = fmaxf(mx, sv[r * HW + i]);
    #pragma unroll
    for (int off = 1; off < 8; off <<= 1) mx = fmaxf(mx, __shfl_xor(mx, off));
    if (p == 0) smax[r] = mx;
  }
  __syncthreads();

  for (int i = tid; i < 1568; i += 256) {
    int r = (i * 1338) >> 16;        // i/49 exact for i<1568
    float v = sv[i] * smax[r];
    pcam[base + i] = (__bf16)v;
  }
}

// ---------------------------------------------------------------------------
// Kernel B: split-K bf16 MFMA GEMM. NO atomics (private partial slices),
// NO global_load_lds (full reg-staging so barriers never drain vmcnt).
// BM=128 BN=128 BK=64, 8 waves (2Mx4N), 2 blocks/CU.
// B prefetched 2 K-steps ahead (2 reg sets, rotated by RELATIVE parity
// (s^s0)&1 — absolute parity broke odd-s0 splits in R3); A 1 step ahead.
// XOR swizzle on ds_write + ds_read: 16B-block idx ^= (row&7).
// Partial output: h_part[ks][n][m] (m fastest so the 4 acc rows are a float4).
// ---------------------------------------------------------------------------
#define BM 128
#define BN 128
#define BK 64
#define MT 2
#define NT 6
#define KSPLIT 42
#define KSTEPS 784          // KDIM/BK

__global__ __launch_bounds__(512, 4) void gemm1_kernel(const __bf16* __restrict__ pcam,
                                                       const float* __restrict__ W1,
                                                       float* __restrict__ h_part) {
  __shared__ __bf16 Asm[2][BM * BK];   // 2 x 16KB
  __shared__ __bf16 Bsm[2][BN * BK];   // 2 x 16KB

  const int tid  = threadIdx.x;
  const int lane = tid & 63;
  const int w    = tid >> 6;        // 0..7
  const int wm   = w >> 2;          // 0..1
  const int wn   = w & 3;           // 0..3
  const int bx   = blockIdx.x;      // 0..11
  const int m0   = (bx & 1) * BM;
  const int n0   = (bx >> 1) * BN;
  const int ks   = blockIdx.y;
  const int s0   = (ks * KSTEPS) / KSPLIT;
  const int s1   = ((ks + 1) * KSTEPS) / KSPLIT;

  // B staging geometry: 4 rows x float4 per thread
  const int nb  = tid >> 4;         // 0..31
  const int kq  = tid & 15;         // float4 within row
  const int kb  = kq >> 1;          // 16B block within row
  const int sub = (kq & 1) << 3;    // byte offset within 16B block
  // A staging geometry: 1 row x 2 16B-blocks per thread
  const int ma  = tid >> 2;         // 0..127
  const int kb0 = (tid & 3) * 2;    // 0,2,4,6

  const float* wbase = W1 + (size_t)(n0 + nb) * KDIM + kq * 4;
  const __bf16* abase = pcam + (size_t)(m0 + ma) * KDIM + kb0 * 8;

  f32x4 acc[4][2];
  #pragma unroll
  for (int i = 0; i < 4; ++i)
    #pragma unroll
    for (int j = 0; j < 2; ++j) acc[i][j] = f32x4{0.f, 0.f, 0.f, 0.f};

  float4 bA0, bA1, bA2, bA3;   // B reg set 0 (holds B(s0 + even offsets))
  float4 bB0, bB1, bB2, bB3;   // B reg set 1 (holds B(s0 + odd offsets))
  bf16x8 ar0, ar1;             // A reg set

#define LOAD_B(R0, R1, R2, R3, s) do { \
    const size_t ko_ = (size_t)(s) * BK; \
    R0 = *(const float4*)(wbase + ko_); \
    R1 = *(const float4*)(wbase + (size_t)32 * KDIM + ko_); \
    R2 = *(const float4*)(wbase + (size_t)64 * KDIM + ko_); \
    R3 = *(const float4*)(wbase + (size_t)96 * KDIM + ko_); \
  } while (0)

#define LOAD_A(s) do { \
    const __bf16* p_ = abase + (size_t)(s) * BK; \
    ar0 = *(const bf16x8*)(p_); \
    ar1 = *(const bf16x8*)(p_ + 8); \
  } while (0)

#define WRITE_B(bi, R0, R1, R2, R3) do { \
    _Pragma("unroll") \
    for (int it = 0; it < 4; ++it) { \
      const float4 v = (it == 0) ? R0 : (it == 1) ? R1 : (it == 2) ? R2 : R3; \
      bf16x4 bv; \
      bv[0] = (__bf16)v.x; bv[1] = (__bf16)v.y; bv[2] = (__bf16)v.z; bv[3] = (__bf16)v.w; \
      const int n = it * 32 + nb; \
      const int phys = n * 128 + (((kb ^ (n & 7)) << 4) | sub); \
      *(bf16x4*)((char*)Bsm[bi] + phys) = bv; \
    } \
  } while (0)

#define WRITE_A(bi) do { \
    const int p0 = ma * 128 + (((kb0 ^ (ma & 7)) << 4)); \
    const int p1 = ma * 128 + ((((kb0 + 1) ^ (ma & 7)) << 4)); \
    *(bf16x8*)((char*)Asm[bi] + p0) = ar0; \
    *(bf16x8*)((char*)Asm[bi] + p1) = ar1; \
  } while (0)

#define COMPUTE(bi) do { \
    _Pragma("unroll") \
    for (int ksub = 0; ksub < 2; ++ksub) { \
      bf16x8 af[4], bfr[2]; \
      const int kb2 = ksub * 4 + (lane >> 4); \
      _Pragma("unroll") \
      for (int i = 0; i < 4; ++i) { \
        const int m = wm * 64 + i * 16 + (lane & 15); \
        af[i] = *(const bf16x8*)((const char*)Asm[bi] + m * 128 + ((kb2 ^ (m & 7)) << 4)); \
      } \
      _Pragma("unroll") \
      for (int j = 0; j < 2; ++j) { \
        const int n = wn * 32 + j * 16 + (lane & 15); \
        bfr[j] = *(const bf16x8*)((const char*)Bsm[bi] + n * 128 + ((kb2 ^ (n & 7)) << 4)); \
      } \
      _Pragma("unroll") \
      for (int i = 0; i < 4; ++i) \
        _Pragma("unroll") \
        for (int j = 0; j < 2; ++j) \
          acc[i][j] = __builtin_amdgcn_mfma_f32_16x16x32_bf16(af[i], bfr[j], acc[i][j], 0, 0, 0); \
    } \
  } while (0)

  // ---- prologue: B(s0) -> set0, B(s0+1) -> set1
  LOAD_B(bA0, bA1, bA2, bA3, s0);
  if (s0 + 1 < s1) LOAD_B(bB0, bB1, bB2, bB3, s0 + 1);
  LOAD_A(s0);
  WRITE_B(s0 & 1, bA0, bA1, bA2, bA3);
  WRITE_A(s0 & 1);
  if (s0 + 1 < s1) LOAD_A(s0 + 1);
  __syncthreads();

  // Invariant entering iter s (rel = (s^s0)&1):
  //   buf[s&1] ready; set[rel^1] holds B(s+1); set[rel] stale (B(s), already
  //   in LDS) and free to refill with B(s+2); A-regs hold A(s+1).
  for (int s = s0; s < s1; ++s) {
    const int cur = s & 1;
    const int rel = (s ^ s0) & 1;
    if (s + 2 < s1) {
      if (rel) LOAD_B(bB0, bB1, bB2, bB3, s + 2);
      else     LOAD_B(bA0, bA1, bA2, bA3, s + 2);
    }
    if (s + 1 < s1) {
      if (rel) WRITE_B(cur ^ 1, bA0, bA1, bA2, bA3);
      else     WRITE_B(cur ^ 1, bB0, bB1, bB2, bB3);
    }
    COMPUTE(cur);
    if (s + 1 < s1) WRITE_A(cur ^ 1);
    if (s + 2 < s1) LOAD_A(s + 2);
    __syncthreads();
  }

  // ---- epilogue: private partial slice, coalesced float4 stores, no atomics
  float* out = h_part + (size_t)ks * DHID * B_SZ;
  #pragma unroll
  for (int i = 0; i < 4; ++i) {
    const int mb = m0 + wm * 64 + i * 16 + (lane >> 4) * 4;
    #pragma unroll
    for (int j = 0; j < 2; ++j) {
      const int n = n0 + wn * 32 + j * 16 + (lane & 15);
      *(f32x4*)(out + (size_t)n * B_SZ + mb) = acc[i][j];
    }
  }
#undef LOAD_B
#undef LOAD_A
#undef WRITE_B
#undef WRITE_A
#undef COMPUTE
}

// ---------------------------------------------------------------------------
// Kernel C: reduce split-K partials, add b1, relu -> h[m][n]
// ---------------------------------------------------------------------------
__global__ __launch_bounds__(256) void reduce_kernel(const float* __restrict__ h_part,
                                                     const float* __restrict__ b1,
                                                     float* __restrict__ h) {
  const int n = blockIdx.x;
  const int m = threadIdx.x;
  float s = 0.f;
  #pragma unroll 6
  for (int ks = 0; ks < KSPLIT; ++ks)
    s += h_part[((size_t)ks * DHID + n) * B_SZ + m];
  float v = s + b1[n];
  h[(size_t)m * DHID + n] = v > 0.f ? v : 0.f;
}

// ---------------------------------------------------------------------------
// Kernel D: logits = h @ W2^T + b2. One wave per batch row.
// ---------------------------------------------------------------------------
__global__ __launch_bounds__(64) void head_kernel(const float* __restrict__ h,
                                                  const float* __restrict__ W2,
                                                  const float* __restrict__ b2,
                                                  float* __restrict__ logits) {
  const int m = blockIdx.x;
  const int lane = threadIdx.x;
  float hv[12];
  #pragma unroll
  for (int j = 0; j < 12; ++j) hv[j] = h[(size_t)m * DHID + j * 64 + lane];
  #pragma unroll
  for (int c = 0; c < NCLS; ++c) {
    float s = 0.f;
    #pragma unroll
    for (int j = 0; j < 12; ++j) s += hv[j] * W2[c * DHID + j * 64 + lane];
    #pragma unroll
    for (int off = 32; off > 0; off >>= 1) s += __shfl_xor(s, off);
    if (lane == 0) logits[m * NCLS + c] = s + b2[c];
  }
}

// ---------------------------------------------------------------------------
extern "C" void kernel_launch(void* const* d_in, const int* in_sizes, int n_in,
                              void* d_out, int out_size, void* d_ws, size_t ws_size,
                              hipStream_t stream) {
  const float* feat = (const float*)d_in[0];
  const float* W1   = (const float*)d_in[1];
  const float* b1   = (const float*)d_in[2];
  const float* W2   = (const float*)d_in[3];
  const float* b2   = (const float*)d_in[4];

  float* logits   = (float*)d_out;
  float* feat_out = (float*)d_out + (size_t)B_SZ * NCLS;

  char* ws = (char*)d_ws;
  __bf16* pcam   = (__bf16*)ws;                                   // 25.7 MB
  float*  h_part = (float*)(ws + (size_t)B_SZ * KDIM * 2);        // 33 MB
  float*  h      = (float*)(ws + (size_t)B_SZ * KDIM * 2
                               + (size_t)KSPLIT * DHID * B_SZ * 4); // 786 KB

  pcam_kernel<<<(B_SZ * C_SZ) / 32, 256, 0, stream>>>(feat, feat_out, pcam);
  gemm1_kernel<<<dim3(MT * NT, KSPLIT), 512, 0, stream>>>(pcam, W1, h_part);
  reduce_kernel<<<DHID, 256, 0, stream>>>(h_part, b1, h);
  head_kernel<<<B_SZ, 64, 0, stream>>>(h, W2, b2, logits);
}

// Round 5
// 107.444 us; speedup vs baseline: 1.0457x; 1.0043x over previous
//
#include <hip/hip_runtime.h>
#include <hip/hip_bf16.h>

// Shapes
#define B_SZ   256
#define C_SZ   1024
#define HW     49
#define KDIM   50176        // C*H*W
#define DHID   768
#define NCLS   5

typedef __bf16 bf16x8 __attribute__((ext_vector_type(8)));
typedef __bf16 bf16x4 __attribute__((ext_vector_type(4)));
typedef float  f32x4  __attribute__((ext_vector_type(4)));

// Counted barrier: make LDS writes visible + rendezvous, but DO NOT drain
// vmcnt — __syncthreads() emits s_waitcnt vmcnt(0) which kills all global
// prefetch depth (the R1-R4 85us plateau). Global-load->register deps are
// handled by the compiler's own precise vmcnt(N) waits.
#define BARRIER() do { \
    asm volatile("s_waitcnt lgkmcnt(0)" ::: "memory"); \
    __builtin_amdgcn_s_barrier(); \
    asm volatile("" ::: "memory"); \
  } while (0)

// ---------------------------------------------------------------------------
// Kernel A: per-(b,c) spatial max, pcam = feat*max -> bf16 (ws), copy feat -> out
// ---------------------------------------------------------------------------
__global__ __launch_bounds__(256) void pcam_kernel(const float* __restrict__ feat,
                                                   float* __restrict__ feat_out,
                                                   __bf16* __restrict__ pcam) {
  __shared__ float sv[1568];
  __shared__ float smax[32];
  const int tid = threadIdx.x;
  const size_t base = (size_t)blockIdx.x * 1568;

  const float4* src4 = (const float4*)(feat + base);
  float4* dst4 = (float4*)(feat_out + base);
  #pragma unroll
  for (int i = 0; i < 2; ++i) {
    int idx = tid + i * 256;
    if (idx < 392) {
      float4 v = src4[idx];
      dst4[idx] = v;
      ((float4*)sv)[idx] = v;
    }
  }
  __syncthreads();

  {
    const int r = tid >> 3, p = tid & 7;
    float mx = -INFINITY;
    for (int i = p; i < HW; i += 8) mx = fmaxf(mx, sv[r * HW + i]);
    #pragma unroll
    for (int off = 1; off < 8; off <<= 1) mx = fmaxf(mx, __shfl_xor(mx, off));
    if (p == 0) smax[r] = mx;
  }
  __syncthreads();

  for (int i = tid; i < 1568; i += 256) {
    int r = (i * 1338) >> 16;        // i/49 exact for i<1568
    float v = sv[i] * smax[r];
    pcam[base + i] = (__bf16)v;
  }
}

// ---------------------------------------------------------------------------
// Kernel B: split-K bf16 MFMA GEMM. No atomics, full reg-staging, and
// counted barriers (BARRIER) so B(s+2)/A(s+2) prefetch stays in flight
// across K-steps. BM=128 BN=128 BK=64, 8 waves (2Mx4N), 2 blocks/CU.
// B reg sets rotate by RELATIVE parity (s^s0)&1. XOR swizzle on
// ds_write/ds_read: 16B-block idx ^= (row&7).
// ---------------------------------------------------------------------------
#define BM 128
#define BN 128
#define BK 64
#define MT 2
#define NT 6
#define KSPLIT 42
#define KSTEPS 784          // KDIM/BK

__global__ __launch_bounds__(512, 4) void gemm1_kernel(const __bf16* __restrict__ pcam,
                                                       const float* __restrict__ W1,
                                                       float* __restrict__ h_part) {
  __shared__ __bf16 Asm[2][BM * BK];   // 2 x 16KB
  __shared__ __bf16 Bsm[2][BN * BK];   // 2 x 16KB

  const int tid  = threadIdx.x;
  const int lane = tid & 63;
  const int w    = tid >> 6;        // 0..7
  const int wm   = w >> 2;          // 0..1
  const int wn   = w & 3;           // 0..3
  const int bx   = blockIdx.x;      // 0..11
  const int m0   = (bx & 1) * BM;
  const int n0   = (bx >> 1) * BN;
  const int ks   = blockIdx.y;
  const int s0   = (ks * KSTEPS) / KSPLIT;
  const int s1   = ((ks + 1) * KSTEPS) / KSPLIT;

  // B staging geometry: 4 rows x float4 per thread
  const int nb  = tid >> 4;         // 0..31
  const int kq  = tid & 15;         // float4 within row
  const int kb  = kq >> 1;          // 16B block within row
  const int sub = (kq & 1) << 3;    // byte offset within 16B block
  // A staging geometry: 1 row x 2 16B-blocks per thread
  const int ma  = tid >> 2;         // 0..127
  const int kb0 = (tid & 3) * 2;    // 0,2,4,6

  const float* wbase = W1 + (size_t)(n0 + nb) * KDIM + kq * 4;
  const __bf16* abase = pcam + (size_t)(m0 + ma) * KDIM + kb0 * 8;

  f32x4 acc[4][2];
  #pragma unroll
  for (int i = 0; i < 4; ++i)
    #pragma unroll
    for (int j = 0; j < 2; ++j) acc[i][j] = f32x4{0.f, 0.f, 0.f, 0.f};

  float4 bA0, bA1, bA2, bA3;   // B reg set 0 (holds B(s0 + even offsets))
  float4 bB0, bB1, bB2, bB3;   // B reg set 1 (holds B(s0 + odd offsets))
  bf16x8 ar0, ar1;             // A reg set

#define LOAD_B(R0, R1, R2, R3, s) do { \
    const size_t ko_ = (size_t)(s) * BK; \
    R0 = *(const float4*)(wbase + ko_); \
    R1 = *(const float4*)(wbase + (size_t)32 * KDIM + ko_); \
    R2 = *(const float4*)(wbase + (size_t)64 * KDIM + ko_); \
    R3 = *(const float4*)(wbase + (size_t)96 * KDIM + ko_); \
  } while (0)

#define LOAD_A(s) do { \
    const __bf16* p_ = abase + (size_t)(s) * BK; \
    ar0 = *(const bf16x8*)(p_); \
    ar1 = *(const bf16x8*)(p_ + 8); \
  } while (0)

#define WRITE_B(bi, R0, R1, R2, R3) do { \
    _Pragma("unroll") \
    for (int it = 0; it < 4; ++it) { \
      const float4 v = (it == 0) ? R0 : (it == 1) ? R1 : (it == 2) ? R2 : R3; \
      bf16x4 bv; \
      bv[0] = (__bf16)v.x; bv[1] = (__bf16)v.y; bv[2] = (__bf16)v.z; bv[3] = (__bf16)v.w; \
      const int n = it * 32 + nb; \
      const int phys = n * 128 + (((kb ^ (n & 7)) << 4) | sub); \
      *(bf16x4*)((char*)Bsm[bi] + phys) = bv; \
    } \
  } while (0)

#define WRITE_A(bi) do { \
    const int p0 = ma * 128 + (((kb0 ^ (ma & 7)) << 4)); \
    const int p1 = ma * 128 + ((((kb0 + 1) ^ (ma & 7)) << 4)); \
    *(bf16x8*)((char*)Asm[bi] + p0) = ar0; \
    *(bf16x8*)((char*)Asm[bi] + p1) = ar1; \
  } while (0)

#define COMPUTE(bi) do { \
    _Pragma("unroll") \
    for (int ksub = 0; ksub < 2; ++ksub) { \
      bf16x8 af[4], bfr[2]; \
      const int kb2 = ksub * 4 + (lane >> 4); \
      _Pragma("unroll") \
      for (int i = 0; i < 4; ++i) { \
        const int m = wm * 64 + i * 16 + (lane & 15); \
        af[i] = *(const bf16x8*)((const char*)Asm[bi] + m * 128 + ((kb2 ^ (m & 7)) << 4)); \
      } \
      _Pragma("unroll") \
      for (int j = 0; j < 2; ++j) { \
        const int n = wn * 32 + j * 16 + (lane & 15); \
        bfr[j] = *(const bf16x8*)((const char*)Bsm[bi] + n * 128 + ((kb2 ^ (n & 7)) << 4)); \
      } \
      _Pragma("unroll") \
      for (int i = 0; i < 4; ++i) \
        _Pragma("unroll") \
        for (int j = 0; j < 2; ++j) \
          acc[i][j] = __builtin_amdgcn_mfma_f32_16x16x32_bf16(af[i], bfr[j], acc[i][j], 0, 0, 0); \
    } \
  } while (0)

  // ---- prologue: B(s0) -> set0, B(s0+1) -> set1
  LOAD_B(bA0, bA1, bA2, bA3, s0);
  if (s0 + 1 < s1) LOAD_B(bB0, bB1, bB2, bB3, s0 + 1);
  LOAD_A(s0);
  WRITE_B(s0 & 1, bA0, bA1, bA2, bA3);
  WRITE_A(s0 & 1);
  if (s0 + 1 < s1) LOAD_A(s0 + 1);
  BARRIER();

  // Invariant entering iter s (rel = (s^s0)&1):
  //   buf[s&1] ready; set[rel^1] holds B(s+1); set[rel] free; A-regs hold A(s+1).
  for (int s = s0; s < s1; ++s) {
    const int cur = s & 1;
    const int rel = (s ^ s0) & 1;
    if (s + 2 < s1) {
      if (rel) LOAD_B(bB0, bB1, bB2, bB3, s + 2);
      else     LOAD_B(bA0, bA1, bA2, bA3, s + 2);
    }
    if (s + 1 < s1) {
      if (rel) WRITE_B(cur ^ 1, bA0, bA1, bA2, bA3);
      else     WRITE_B(cur ^ 1, bB0, bB1, bB2, bB3);
    }
    COMPUTE(cur);
    if (s + 1 < s1) WRITE_A(cur ^ 1);
    if (s + 2 < s1) LOAD_A(s + 2);
    BARRIER();
  }

  // ---- epilogue: private partial slice, coalesced float4 stores, no atomics
  float* out = h_part + (size_t)ks * DHID * B_SZ;
  #pragma unroll
  for (int i = 0; i < 4; ++i) {
    const int mb = m0 + wm * 64 + i * 16 + (lane >> 4) * 4;
    #pragma unroll
    for (int j = 0; j < 2; ++j) {
      const int n = n0 + wn * 32 + j * 16 + (lane & 15);
      *(f32x4*)(out + (size_t)n * B_SZ + mb) = acc[i][j];
    }
  }
#undef LOAD_B
#undef LOAD_A
#undef WRITE_B
#undef WRITE_A
#undef COMPUTE
}

// ---------------------------------------------------------------------------
// Kernel C: reduce split-K partials, add b1, relu -> h[m][n]
// ---------------------------------------------------------------------------
__global__ __launch_bounds__(256) void reduce_kernel(const float* __restrict__ h_part,
                                                     const float* __restrict__ b1,
                                                     float* __restrict__ h) {
  const int n = blockIdx.x;
  const int m = threadIdx.x;
  float s = 0.f;
  #pragma unroll 6
  for (int ks = 0; ks < KSPLIT; ++ks)
    s += h_part[((size_t)ks * DHID + n) * B_SZ + m];
  float v = s + b1[n];
  h[(size_t)m * DHID + n] = v > 0.f ? v : 0.f;
}

// ---------------------------------------------------------------------------
// Kernel D: logits = h @ W2^T + b2. One wave per batch row.
// ---------------------------------------------------------------------------
__global__ __launch_bounds__(64) void head_kernel(const float* __restrict__ h,
                                                  const float* __restrict__ W2,
                                                  const float* __restrict__ b2,
                                                  float* __restrict__ logits) {
  const int m = blockIdx.x;
  const int lane = threadIdx.x;
  float hv[12];
  #pragma unroll
  for (int j = 0; j < 12; ++j) hv[j] = h[(size_t)m * DHID + j * 64 + lane];
  #pragma unroll
  for (int c = 0; c < NCLS; ++c) {
    float s = 0.f;
    #pragma unroll
    for (int j = 0; j < 12; ++j) s += hv[j] * W2[c * DHID + j * 64 + lane];
    #pragma unroll
    for (int off = 32; off > 0; off >>= 1) s += __shfl_xor(s, off);
    if (lane == 0) logits[m * NCLS + c] = s + b2[c];
  }
}

// ---------------------------------------------------------------------------
extern "C" void kernel_launch(void* const* d_in, const int* in_sizes, int n_in,
                              void* d_out, int out_size, void* d_ws, size_t ws_size,
                              hipStream_t stream) {
  const float* feat = (const float*)d_in[0];
  const float* W1   = (const float*)d_in[1];
  const float* b1   = (const float*)d_in[2];
  const float* W2   = (const float*)d_in[3];
  const float* b2   = (const float*)d_in[4];

  float* logits   = (float*)d_out;
  float* feat_out = (float*)d_out + (size_t)B_SZ * NCLS;

  char* ws = (char*)d_ws;
  __bf16* pcam   = (__bf16*)ws;                                   // 25.7 MB
  float*  h_part = (float*)(ws + (size_t)B_SZ * KDIM * 2);        // 33 MB
  float*  h      = (float*)(ws + (size_t)B_SZ * KDIM * 2
                               + (size_t)KSPLIT * DHID * B_SZ * 4); // 786 KB

  pcam_kernel<<<(B_SZ * C_SZ) / 32, 256, 0, stream>>>(feat, feat_out, pcam);
  gemm1_kernel<<<dim3(MT * NT, KSPLIT), 512, 0, stream>>>(pcam, W1, h_part);
  reduce_kernel<<<DHID, 256, 0, stream>>>(h_part, b1, h);
  head_kernel<<<B_SZ, 64, 0, stream>>>(h, W2, b2, logits);
}